// Round 12
// baseline (158.850 us; speedup 1.0000x reference)
//
#include <hip/hip_runtime.h>

// pred/target (4,4,64,128,128) fp32 -> 16 volumes of 64x128x128.
#define NB 16
#define DD 64
#define HH 128
#define WW 128
#define HW (HH * WW)

constexpr int TH = 8;              // output rows per block
constexpr int LY = TH + 2;         // 10 input rows
constexpr int PL = LY * WW;        // slab size = 1280 floats = 5 KB
constexpr int CDO = 8;             // output planes per block
constexpr int NK = CDO + 2;        // 10 input planes per block
constexpr float INV_COUNT = 1.0f / 50331648.0f; // 1/(3*16*64*128*128)

__global__ void zero_out_kernel(float* out) {
    if (threadIdx.x == 0 && blockIdx.x == 0) out[0] = 0.0f;
}

__global__ __launch_bounds__(256) void sobel_l1_kernel(
    const float* __restrict__ pred,
    const float* __restrict__ target,
    float* __restrict__ out)
{
    // 4-slab plane ring: each input plane loaded ONCE, read for 3 output planes.
    __shared__ float S[4][PL];     // 20480 B
    __shared__ float wsum[4];

    const int tid = threadIdx.x;
    int b = blockIdx.x;            // 2048 blocks: 16 bh x 8 dq x 16 bn
    const int bh = b & 15; b >>= 4;
    const int dq = b & 7;  b >>= 3;
    const int bn = b;

    const int h0 = bh * TH;
    const int d0 = dq * CDO;       // output planes d0..d0+7; inputs d0-1..d0+8
    const size_t nbase = (size_t)bn * (size_t)(DD * HW);

    // ---- staging slots: 320 float4/plane over 256 threads ----
    // slot0: i = tid (rows 0..7). slot1: i2 = 256 + (tid>>2), threads with
    // (tid&3)==0 (rows 8..9) — 16 active lanes in EVERY wave (balanced).
    const int y0  = tid >> 5;
    const int gh0 = h0 - 1 + y0;
    const bool okh0 = (unsigned)gh0 < HH;
    const int off0 = min(max(gh0, 0), HH - 1) * WW + 4 * (tid & 31);

    const bool has1 = (tid & 3) == 0;
    const int i2  = 256 + (tid >> 2);
    const int y1  = i2 >> 5;                 // 8..9
    const int gh1 = h0 - 1 + y1;
    const bool okh1 = has1 && ((unsigned)gh1 < HH);
    const int off1 = min(max(gh1, 0), HH - 1) * WW + 4 * (i2 & 31);

    float4 stp[2][2], stq[2][2];   // [set][slot] staging registers

    auto load_st = [&](int k, int set) {     // input plane k (0..9)
        const int gd  = d0 - 1 + k;
        const int gdc = min(max(gd, 0), DD - 1);
        const size_t pb = nbase + (size_t)gdc * HW;
        stp[set][0] = *(const float4*)(pred   + pb + off0);
        stq[set][0] = *(const float4*)(target + pb + off0);
        if (has1) {
            stp[set][1] = *(const float4*)(pred   + pb + off1);
            stq[set][1] = *(const float4*)(target + pb + off1);
        }
    };

    auto store_st = [&](int k, int set) {
        const int gd = d0 - 1 + k;
        const bool zok = (unsigned)gd < DD;
        float* B = S[k & 3];
        {
            const float m = (zok && okh0) ? 1.0f : 0.0f;
            const float4 p = stp[set][0], q = stq[set][0];
            *(float4*)&B[4 * tid] = float4{(p.x - q.x) * m, (p.y - q.y) * m,
                                           (p.z - q.z) * m, (p.w - q.w) * m};
        }
        if (has1) {
            const float m = (zok && okh1) ? 1.0f : 0.0f;
            const float4 p = stp[set][1], q = stq[set][1];
            *(float4*)&B[4 * i2] = float4{(p.x - q.x) * m, (p.y - q.y) * m,
                                          (p.z - q.z) * m, (p.w - q.w) * m};
        }
    };

    const int tc = tid & 31;       // w-quad
    const int lh = tid >> 5;       // output row 0..7

    float4 rA[3], rBh[3], rBw[3];  // per-input-plane partials, ring k%3

    // plane partials from slab k&3: A = s(h)s(w)v, Bh = d(h)s(w)v, Bw = s(h)d(w)v
    auto planeP = [&](int k) {
        const float* B = S[k & 3];
        float4 rs[3], rdw[3];
#pragma unroll
        for (int r = 0; r < 3; ++r) {
            const float4 v = *(const float4*)&B[(lh + r) * WW + 4 * tc];
            float lm = __shfl_up(v.w, 1, 32);
            float rp = __shfl_down(v.x, 1, 32);
            if (tc == 0)  lm = 0.f;
            if (tc == 31) rp = 0.f;
            rs[r]  = float4{lm  + 2.f * v.x + v.y,
                            v.x + 2.f * v.y + v.z,
                            v.y + 2.f * v.z + v.w,
                            v.z + 2.f * v.w + rp};
            rdw[r] = float4{v.y - lm, v.z - v.x, v.w - v.y, rp - v.z};
        }
        const int j = k % 3;
        rA[j]  = float4{rs[0].x + 2.f * rs[1].x + rs[2].x,
                        rs[0].y + 2.f * rs[1].y + rs[2].y,
                        rs[0].z + 2.f * rs[1].z + rs[2].z,
                        rs[0].w + 2.f * rs[1].w + rs[2].w};
        rBh[j] = float4{rs[2].x - rs[0].x, rs[2].y - rs[0].y,
                        rs[2].z - rs[0].z, rs[2].w - rs[0].w};
        rBw[j] = float4{rdw[0].x + 2.f * rdw[1].x + rdw[2].x,
                        rdw[0].y + 2.f * rdw[1].y + rdw[2].y,
                        rdw[0].z + 2.f * rdw[1].z + rdw[2].z,
                        rdw[0].w + 2.f * rdw[1].w + rdw[2].w};
    };

    // ---- prologue: planes 0,1 staged+stored; 2,3 loaded (2-deep prefetch) ----
    float acc = 0.0f;
    load_st(0, 0); load_st(1, 1);
    store_st(0, 0); load_st(2, 0);
    store_st(1, 1); load_st(3, 1);
    __syncthreads();
    planeP(0); planeP(1);

    // ---- plane-tick loop: one new input plane per tick, one barrier ----
    for (int t = 0; t < CDO; ++t) {
        const int set = t & 1;
        store_st(t + 2, set);                 // slab (t+2)&3: WAR-safe (>=2 syncs old)
        if (t + 4 < NK) load_st(t + 4, set);  // 2 ticks of prefetch depth
        __syncthreads();
        planeP(t + 2);
        const int s0 = t % 3, s1 = (t + 1) % 3, s2 = (t + 2) % 3;
        const float4 a0 = rA[s0],  a2 = rA[s2];
        const float4 b0 = rBh[s0], b1 = rBh[s1], b2 = rBh[s2];
        const float4 c0 = rBw[s0], c1 = rBw[s1], c2 = rBw[s2];
        acc += fabsf(a2.x - a0.x) + fabsf(a2.y - a0.y)
             + fabsf(a2.z - a0.z) + fabsf(a2.w - a0.w);
        acc += fabsf(b0.x + 2.f * b1.x + b2.x) + fabsf(b0.y + 2.f * b1.y + b2.y)
             + fabsf(b0.z + 2.f * b1.z + b2.z) + fabsf(b0.w + 2.f * b1.w + b2.w);
        acc += fabsf(c0.x + 2.f * c1.x + c2.x) + fabsf(c0.y + 2.f * c1.y + c2.y)
             + fabsf(c0.z + 2.f * c1.z + c2.z) + fabsf(c0.w + 2.f * c1.w + c2.w);
    }

    // ---- block reduction ----
#pragma unroll
    for (int off = 32; off > 0; off >>= 1)
        acc += __shfl_down(acc, off, 64);
    if ((tid & 63) == 0) wsum[tid >> 6] = acc;
    __syncthreads();
    if (tid == 0) {
        const float s = wsum[0] + wsum[1] + wsum[2] + wsum[3];
        atomicAdd(out, s * INV_COUNT);
    }
}

extern "C" void kernel_launch(void* const* d_in, const int* in_sizes, int n_in,
                              void* d_out, int out_size, void* d_ws, size_t ws_size,
                              hipStream_t stream) {
    const float* pred   = (const float*)d_in[0];
    const float* target = (const float*)d_in[1];
    float* out = (float*)d_out;

    zero_out_kernel<<<1, 64, 0, stream>>>(out);

    // 16 volumes * 8 d-runs * 16 h-tiles = 2048 blocks
    const int nblocks = NB * (DD / CDO) * (HH / TH);
    sobel_l1_kernel<<<nblocks, 256, 0, stream>>>(pred, target, out);
}